// Round 12
// baseline (179.661 us; speedup 1.0000x reference)
//
#include <hip/hip_runtime.h>
#include <hip/hip_fp16.h>

// ButterflyRotation: 12 butterfly layers over rows of 4096 fp32.
// R12: R10 structure (BLOCK=512, 2 rows packed v2f in interleaved 32 KiB
// LDS, radix-8 x 4 phases, f16 {1-cos,sin} table, lgkm-only barriers) with
// TWO row-pairs per block pipelined through the same LDS: pair B's x-loads
// issue during pair A's P3; A's stores overlap B's P1. Grid 2048 (3
// blocks/CU resident -> dispatch wavefront + L3 locality preserved).
// d-form rotation (keep d=1-cos; 4 pk-fma, no reconstruction subs).
//   P1: e = 8t+m                    -> layers 0-2   (x direct from global)
//   P2: e = 64(t>>3)+8m+(t&7)       -> layers 3-5
//   P3: e = 512(t>>6)+64m+(t&63)    -> layers 6-8
//   P4: e = t+512m                  -> layers 9-11  (coalesced store)

#define DIM    4096
#define LAYERS 12
#define BATCH  8192
#define NANG   2048
#define BLOCK  512
#define GRID   (BATCH / 4)          // 2048 blocks x 4 rows

typedef unsigned int u32;
typedef float v2f __attribute__((ext_vector_type(2)));

// lgkm-only barrier: global loads/stores stay in flight across it
#define BAR() do {                                             \
    asm volatile("s_waitcnt lgkmcnt(0)" ::: "memory");         \
    __builtin_amdgcn_sched_barrier(0);                         \
    __builtin_amdgcn_s_barrier();                              \
} while (0)

// quad-level swizzle (involution: only bits 0-2 change)
__device__ __forceinline__ int swzQ(int Q) {
    return Q ^ ((Q >> 3) & 7) ^ ((Q >> 6) & 7);
}
// element -> interleaved 8B-unit slot (quad swizzle in packed space)
__device__ __forceinline__ int uslot(int e) {
    return 2 * swzQ(e >> 1) + (e & 1);
}
// butterfly sub-index for left element m at local level jj (stride 2^jj)
__device__ __forceinline__ constexpr int inner_idx(int m, int jj) {
    return ((m >> (jj + 1)) << jj) + (m & ((1 << jj) - 1));
}

// d-form packed rotation: d = 1-cos, s = sin.  4 pk-fma:
// c*xl = fma(-d,xl,xl); nl = fma(s,xr,c*xl); nr = fma(-s,xl,c*xr).
__device__ __forceinline__ void rot2d(v2f& xl, v2f& xr, float d, float s) {
    v2f cl = xl - d * xl;
    v2f cr = xr - d * xr;
    v2f nl = cl + s * xr;
    v2f nr = cr - s * xl;
    xl = nl; xr = nr;
}

// f16-packed transposed table (identical layout to R10): 12 groups x 512
// threads x uint4; u32 component a&3 of group (region*3 + (a>>2)) holds
// angle a = jj*4+ii of that phase for thread t, packed {h(1-c) | h(s)<<16}.
__global__ void __launch_bounds__(256) cs_kernel(const float* __restrict__ angles,
                                                 u32* __restrict__ TH, int n) {
    int i = blockIdx.x * blockDim.x + threadIdx.x;
    if (i >= n) return;
    float a = angles[i];
    float c = cosf(a), s = sinf(a);
    int l = i >> 11, aa = i & 2047;
    int region, jj, t, ii;
    if (l < 3)      { region = 0; jj = l;     t = aa >> 2;  ii = aa & 3; }
    else if (l < 6) { region = 1; jj = l - 3; int B = aa >> 5, r = aa & 31;
                      ii = r >> 3; t = 8 * B + (r & 7); }
    else if (l < 9) { region = 2; jj = l - 6; int S = aa >> 8, r = aa & 255;
                      ii = r >> 6; t = 64 * S + (r & 63); }
    else            { region = 3; jj = l - 9; ii = aa >> 9; t = aa & 511; }
    int a_idx = jj * 4 + ii;
    int flat = ((region * 3 + (a_idx >> 2)) * 512 + t) * 4 + (a_idx & 3);
    u32 lo = (u32)__half_as_ushort(__float2half(1.0f - c));
    u32 hi = (u32)__half_as_ushort(__float2half(s));
    TH[flat] = lo | (hi << 16);
}

// unpack 3 uint4 -> 12 (d,s) pairs (compile-time indices after unroll)
#define UNPACK12(Ua, Ub, Uc, dd, ss) do {                                  \
    const u32 _u[12] = {Ua.x, Ua.y, Ua.z, Ua.w, Ub.x, Ub.y, Ub.z, Ub.w,    \
                        Uc.x, Uc.y, Uc.z, Uc.w};                           \
    _Pragma("unroll")                                                      \
    for (int a = 0; a < 12; ++a) {                                         \
        __half2 h2 = *reinterpret_cast<const __half2*>(&_u[a]);            \
        float2 f = __half22float2(h2);                                     \
        dd[a] = f.x; ss[a] = f.y;                                          \
    }                                                                      \
} while (0)

// one phase = 3 layers (local strides 1,2,4) on packed w[8]
#define PHASE_ROTS(dd, ss, w)                                              \
    _Pragma("unroll")                                                      \
    for (int jj = 0; jj < 3; ++jj) {                                       \
        const int st = 1 << jj;                                            \
        _Pragma("unroll")                                                  \
        for (int m = 0; m < 8; ++m) {                                      \
            if (!(m & st)) {                                               \
                const int a = jj * 4 + inner_idx(m, jj);                   \
                rot2d(w[m], w[m + st], dd[a], ss[a]);                      \
            }                                                              \
        }                                                                  \
    }

__global__ void __launch_bounds__(BLOCK, 6)
butterfly_kernel(const float* __restrict__ x, const uint4* __restrict__ TH4,
                 float* __restrict__ out) {
    __shared__ v2f buf[DIM];                // 32 KiB interleaved {r0[e], r1[e]}
    const int t = threadIdx.x;
    const long base = (long)blockIdx.x * 4; // 4 rows: pair0 = base,base+1; pair1 = base+2,base+3

    v2f w[8];
    float dd[12], ss[12];
    float4 xa0, xa1, xa2, xa3;              // pair-0 x (loaded in prologue)
    float4 xb0, xb1, xb2, xb3;              // pair-1 x (prefetched during q=0 P3)
    uint4 U0, U1, U2;                       // current-phase angles

    // ---- prologue: pair-0 x first (longest latency), then P1 angles ----
    {
        const float* p0 = x + base * DIM + 8 * t;
        xa0 = *(const float4*)(p0);
        xa1 = *(const float4*)(p0 + 4);
        xa2 = *(const float4*)(p0 + DIM);
        xa3 = *(const float4*)(p0 + DIM + 4);
        U0 = TH4[0 * 512 + t]; U1 = TH4[1 * 512 + t]; U2 = TH4[2 * 512 + t];
    }

    #pragma unroll
    for (int q = 0; q < 2; ++q) {
        // ===== P1: e = 8t+k, layers 0-2 =====
        {
            float4 a = (q == 0) ? xa0 : xb0;
            float4 b = (q == 0) ? xa1 : xb1;
            float4 c = (q == 0) ? xa2 : xb2;
            float4 d = (q == 0) ? xa3 : xb3;
            // prefetch P2 angles (fly across BAR)
            uint4 V0 = TH4[3 * 512 + t], V1 = TH4[4 * 512 + t], V2 = TH4[5 * 512 + t];
            w[0] = v2f{a.x, c.x}; w[1] = v2f{a.y, c.y};
            w[2] = v2f{a.z, c.z}; w[3] = v2f{a.w, c.w};
            w[4] = v2f{b.x, d.x}; w[5] = v2f{b.y, d.y};
            w[6] = v2f{b.z, d.z}; w[7] = v2f{b.w, d.w};
            UNPACK12(U0, U1, U2, dd, ss);
            PHASE_ROTS(dd, ss, w)
            #pragma unroll
            for (int wq = 0; wq < 4; ++wq) {
                *(float4*)(&buf[2 * swzQ(4 * t + wq)]) =
                    make_float4(w[2*wq].x, w[2*wq].y, w[2*wq+1].x, w[2*wq+1].y);
            }
            U0 = V0; U1 = V1; U2 = V2;
        }
        BAR();

        // ===== P2: e = 64(t>>3) + 8m + (t&7), layers 3-5 (b64) =====
        {
            uint4 V0 = TH4[6 * 512 + t], V1 = TH4[7 * 512 + t], V2 = TH4[8 * 512 + t];
            const int eb = 64 * (t >> 3) + (t & 7);
            int ps[8];
            #pragma unroll
            for (int m = 0; m < 8; ++m) {
                ps[m] = uslot(eb + 8 * m);
                w[m] = buf[ps[m]];
            }
            UNPACK12(U0, U1, U2, dd, ss);
            PHASE_ROTS(dd, ss, w)
            #pragma unroll
            for (int m = 0; m < 8; ++m) buf[ps[m]] = w[m];   // own slots
            U0 = V0; U1 = V1; U2 = V2;
        }
        BAR();

        // ===== P3: e = 512(t>>6) + 64m + (t&63), layers 6-8 (b64) =====
        {
            uint4 V0 = TH4[9 * 512 + t], V1 = TH4[10 * 512 + t], V2 = TH4[11 * 512 + t];
            // prefetch pair-1 x here: ~2 phases ahead of its use
            if (q == 0) {
                const float* p1 = x + (base + 2) * DIM + 8 * t;
                xb0 = *(const float4*)(p1);
                xb1 = *(const float4*)(p1 + 4);
                xb2 = *(const float4*)(p1 + DIM);
                xb3 = *(const float4*)(p1 + DIM + 4);
            }
            const int eb = 512 * (t >> 6) + (t & 63);
            int ps[8];
            #pragma unroll
            for (int m = 0; m < 8; ++m) {
                ps[m] = uslot(eb + 64 * m);
                w[m] = buf[ps[m]];
            }
            UNPACK12(U0, U1, U2, dd, ss);
            PHASE_ROTS(dd, ss, w)
            #pragma unroll
            for (int m = 0; m < 8; ++m) buf[ps[m]] = w[m];
            U0 = V0; U1 = V1; U2 = V2;
        }
        BAR();

        // ===== P4: e = t + 512m, layers 9-11 (b64); store =====
        {
            // reload P1 angles for pair 1 (L1-hot)
            uint4 V0, V1, V2;
            if (q == 0) {
                V0 = TH4[0 * 512 + t]; V1 = TH4[1 * 512 + t]; V2 = TH4[2 * 512 + t];
            }
            #pragma unroll
            for (int m = 0; m < 8; ++m) w[m] = buf[uslot(t + 512 * m)];
            UNPACK12(U0, U1, U2, dd, ss);
            PHASE_ROTS(dd, ss, w)
            float* o0 = out + (base + 2 * q) * DIM + t;
            float* o1 = o0 + DIM;
            #pragma unroll
            for (int m = 0; m < 8; ++m) {
                o0[m << 9] = w[m].x;
                o1[m << 9] = w[m].y;
            }
            if (q == 0) { U0 = V0; U1 = V1; U2 = V2; }
        }
        BAR();   // protects pair-1 P1 LDS writes vs this P4's reads
    }
}

extern "C" void kernel_launch(void* const* d_in, const int* in_sizes, int n_in,
                              void* d_out, int out_size, void* d_ws, size_t ws_size,
                              hipStream_t stream) {
    (void)in_sizes; (void)n_in; (void)out_size; (void)ws_size;
    const float* x      = (const float*)d_in[0];
    const float* angles = (const float*)d_in[1];
    float* out = (float*)d_out;

    const int n = LAYERS * NANG;                    // 24576 angles, 96 KiB table
    cs_kernel<<<(n + 255) / 256, 256, 0, stream>>>(angles, (u32*)d_ws, n);
    butterfly_kernel<<<GRID, BLOCK, 0, stream>>>(x, (const uint4*)d_ws, out);
}